// Round 5
// baseline (250.148 us; speedup 1.0000x reference)
//
#include <hip/hip_runtime.h>

#define BB 8
#define CC 256
#define DD 128
#define NN 4096
#define BN_EPS 1e-5f

typedef _Float16 f16;
typedef _Float16 half8 __attribute__((ext_vector_type(8)));
typedef float f32x4 __attribute__((ext_vector_type(4)));

__device__ __forceinline__ f32x4 mfma16(half8 a, half8 b, f32x4 c) {
  return __builtin_amdgcn_mfma_f32_16x16x32_f16(a, b, c, 0, 0, 0);
}

__device__ __forceinline__ void gload_lds16(const void* g, void* l) {
  __builtin_amdgcn_global_load_lds((const __attribute__((address_space(1))) void*)g,
                                   (__attribute__((address_space(3))) void*)l, 16, 0, 0);
}

#if __has_builtin(__builtin_amdgcn_exp2f)
#define EXP2(x) __builtin_amdgcn_exp2f(x)
#else
#define EXP2(x) __expf((x)*0.69314718f)
#endif

// 16-lane butterfly reduce via DPP
template <int CTRL>
__device__ __forceinline__ float dpp_mv(float x) {
  int v = __builtin_bit_cast(int, x);
  return __builtin_bit_cast(float, __builtin_amdgcn_update_dpp(0, v, CTRL, 0xF, 0xF, true));
}
__device__ __forceinline__ float dpp_add16(float x) {
  x += dpp_mv<0xB1>(x);
  x += dpp_mv<0x4E>(x);
  x += dpp_mv<0x141>(x);
  x += dpp_mv<0x140>(x);
  return x;
}
__device__ __forceinline__ float dpp_max16(float x) {
  x = fmaxf(x, dpp_mv<0xB1>(x));
  x = fmaxf(x, dpp_mv<0x4E>(x));
  x = fmaxf(x, dpp_mv<0x141>(x));
  x = fmaxf(x, dpp_mv<0x140>(x));
  return x;
}

// ---------- weights cast (fp32 -> fp16), stats zero ----------
__global__ void k_cast_weights(const float* __restrict__ tw, const float* __restrict__ pw,
                               const float* __restrict__ gw, const float* __restrict__ ww,
                               f16* __restrict__ Wcat, f16* __restrict__ Wwh,
                               float* __restrict__ stats) {
  int i = blockIdx.x * 256 + threadIdx.x;
  if (i < 32768) Wcat[i] = (f16)tw[i];
  else if (i < 65536) Wcat[i] = (f16)pw[i - 32768];
  else if (i < 98304) Wcat[i] = (f16)gw[i - 65536];
  else if (i < 131072) Wwh[i - 98304] = (f16)ww[i - 98304];
  if (i < 512) stats[i] = 0.f;
}

// ---------- x [B][C][N] f32 -> xT [B][N][C] f16 ----------
__global__ void k_transpose_x(const float* __restrict__ x, f16* __restrict__ xT) {
  __shared__ f16 tile[32][33];
  int b = blockIdx.z, c0 = blockIdx.y * 32, n0 = blockIdx.x * 32;
  int tx = threadIdx.x, ty = threadIdx.y;
  const float* xp = x + ((size_t)b * CC + c0) * NN + n0;
  for (int j = 0; j < 4; ++j) {
    int cc = ty + j * 8;
    tile[cc][tx] = (f16)xp[(size_t)cc * NN + tx];
  }
  __syncthreads();
  f16* xo = xT + ((size_t)b * NN + n0) * CC + c0;
  for (int j = 0; j < 4; ++j) {
    int nn = ty + j * 8;
    xo[(size_t)nn * CC + tx] = tile[tx][nn];
  }
}

// ---------- projections ----------
__global__ __launch_bounds__(256) void k_gemm1(const f16* __restrict__ xT, const f16* __restrict__ Wcat,
                                               f16* __restrict__ T, f16* __restrict__ P,
                                               f16* __restrict__ Gnd) {
  int b = blockIdx.z;
  int lane = threadIdx.x & 63, wave = threadIdx.x >> 6;
  int lr = lane & 15, lg = lane >> 4;
  int wr = wave >> 1, wc = wave & 1;
  int m0 = blockIdx.x * 64 + wr * 32;
  int c0 = blockIdx.y * 64 + wc * 32;
  const f16* A = xT + (size_t)b * NN * CC;
  f32x4 acc[2][2] = {};
  for (int k0 = 0; k0 < CC; k0 += 32) {
    half8 a[2], w[2];
    for (int i = 0; i < 2; ++i)
      a[i] = *(const half8*)(A + (size_t)(m0 + i * 16 + lr) * CC + k0 + lg * 8);
    for (int j = 0; j < 2; ++j)
      w[j] = *(const half8*)(Wcat + (size_t)(c0 + j * 16 + lr) * CC + k0 + lg * 8);
    for (int i = 0; i < 2; ++i)
      for (int j = 0; j < 2; ++j)
        acc[i][j] = mfma16(a[i], w[j], acc[i][j]);
  }
  for (int i = 0; i < 2; ++i)
    for (int j = 0; j < 2; ++j)
      for (int r = 0; r < 4; ++r) {
        int row = m0 + i * 16 + lg * 4 + r;
        int col = c0 + j * 16 + lr;
        f16 v = (f16)acc[i][j][r];
        size_t base = (size_t)b * NN + row;
        if (col < DD) T[base * DD + col] = v;
        else if (col < 2 * DD) P[base * DD + col - DD] = v;
        else Gnd[base * DD + col - 2 * DD] = v;
      }
}

// ---------- Gnd [B][N][D] -> Gdn [B][D][N] ----------
__global__ void k_transpose_g(const f16* __restrict__ Gnd, f16* __restrict__ Gdn) {
  __shared__ f16 tile[32][33];
  int b = blockIdx.z, d0 = blockIdx.y * 32, n0 = blockIdx.x * 32;
  int tx = threadIdx.x, ty = threadIdx.y;
  for (int j = 0; j < 4; ++j) {
    int nn = ty + j * 8;
    tile[nn][tx] = Gnd[((size_t)b * NN + n0 + nn) * DD + d0 + tx];
  }
  __syncthreads();
  for (int j = 0; j < 4; ++j) {
    int dd = ty + j * 8;
    Gdn[((size_t)b * DD + d0 + dd) * NN + n0 + tx] = tile[tx][dd];
  }
}

// ---------- flash attention ----------
// 2 waves/block, each wave owns TWO 16-row q-tiles (32 q); KV block 64.
// K/V LDS fragments read once, feed both tiles (2x MFMA per ds_read).
// LDS: K dbuf 2x16KB + V dbuf 2x16KB (XOR-swizzled) + P 4 x 16x64 swizzled tiles (2KB) = 72KB.
// Sync: 2 barriers/iter, counted vmcnt(16); 24 loads max in flight, never drained mid-loop.
// Softmax in exp2 domain (Q pre-scaled by log2e); defer-max THR = 11.5 (=8*log2e).
__global__ __launch_bounds__(128) void k_flash(const f16* __restrict__ T, const f16* __restrict__ P,
                                               const f16* __restrict__ Gdn, f16* __restrict__ Y) {
  __shared__ char smem[73728];
  int bid = blockIdx.x;
  int b = bid & 7;  // batch -> XCD pinning
  int qx = bid >> 3;
  int tid = threadIdx.x;            // 0..127
  int lane = tid & 63, wave = tid >> 6;
  int lr = lane & 15, lg = lane >> 4;
  int q0 = qx * 64 + wave * 32;     // tiles at q0, q0+16
  const f16* Tb = T + (size_t)b * NN * DD;
  const f16* Pb = P + (size_t)b * NN * DD;
  const f16* Vb = Gdn + (size_t)b * DD * NN;
  char* Pt[2] = {smem + 65536 + (wave * 2 + 0) * 2048, smem + 65536 + (wave * 2 + 1) * 2048};

  half8 qf[2][4];
  for (int q = 0; q < 2; ++q)
    for (int ks = 0; ks < 4; ++ks) {
      half8 v = *(const half8*)(Tb + (size_t)(q0 + q * 16 + lr) * DD + ks * 32 + lg * 8);
      for (int j = 0; j < 8; ++j) v[j] *= (f16)1.44269504f;  // log2(e) into Q
      qf[q][ks] = v;
    }
  f32x4 acc[2][8] = {};
  float m_run[2][4], l_run[2][4];
  for (int q = 0; q < 2; ++q)
    for (int r = 0; r < 4; ++r) { m_run[q][r] = -1e30f; l_run[q][r] = 0.f; }

  // prologue: stage K(0), V(0)
#pragma unroll
  for (int inst = 0; inst < 8; ++inst) {
    int t = inst * 128 + tid;
    int row = t >> 4, sp = t & 15, sl = sp ^ (row & 7);
    gload_lds16(Pb + (size_t)row * DD + sl * 8, smem + t * 16);
  }
#pragma unroll
  for (int inst = 0; inst < 8; ++inst) {
    int t = inst * 128 + tid;
    int row = t >> 3, sp = t & 7, sl = sp ^ (row & 7);
    gload_lds16(Vb + (size_t)row * NN + sl * 8, smem + 32768 + t * 16);
  }

  for (int kb = 0; kb < 64; ++kb) {
    int key0 = kb * 64;
    int keyn = (kb < 63) ? key0 + 64 : 0;  // last prefetch harmless
    char* Kc = smem + (kb & 1) * 16384;
    char* Kn = smem + ((kb + 1) & 1) * 16384;
    char* Vc = smem + 32768 + (kb & 1) * 16384;
    char* Vn = smem + 32768 + ((kb + 1) & 1) * 16384;

    // issue K(kb+1); target buffer's last reader (QK kb-1) done before B2(kb-1)
#pragma unroll
    for (int inst = 0; inst < 8; ++inst) {
      int t = inst * 128 + tid;
      int row = t >> 4, sp = t & 15, sl = sp ^ (row & 7);
      gload_lds16(Pb + (size_t)(keyn + row) * DD + sl * 8, Kn + t * 16);
    }
    asm volatile("s_waitcnt vmcnt(16)" ::: "memory");  // K(kb) done; V(kb)+K(kb+1) in flight
    __builtin_amdgcn_sched_barrier(0);
    __builtin_amdgcn_s_barrier();  // B1
    __builtin_amdgcn_sched_barrier(0);

    // QK^T: kf read once, both q-tiles consume
    f32x4 s[2][4];
    __builtin_amdgcn_s_setprio(1);
    for (int kt = 0; kt < 4; ++kt) {
      half8 kf[4];
      for (int ks = 0; ks < 4; ++ks)
        kf[ks] = *(const half8*)(Kc + (kt * 16 + lr) * 256 + (((ks * 4 + lg) ^ (lr & 7)) << 4));
      for (int q = 0; q < 2; ++q) {
        f32x4 t = {};
        for (int ks = 0; ks < 4; ++ks) t = mfma16(qf[q][ks], kf[ks], t);
        s[q][kt] = t;
      }
    }
    __builtin_amdgcn_s_setprio(0);

    // online softmax (log2 domain), defer-max
    for (int q = 0; q < 2; ++q) {
      float mx[4];
      for (int r = 0; r < 4; ++r) {
        float m = fmaxf(fmaxf(s[q][0][r], s[q][1][r]), fmaxf(s[q][2][r], s[q][3][r]));
        mx[r] = dpp_max16(m);
      }
      bool grow = false;
      for (int r = 0; r < 4; ++r) grow |= (mx[r] > m_run[q][r] + 11.5f);
      if (__ballot(grow)) {
        for (int r = 0; r < 4; ++r) {
          float mn = fmaxf(m_run[q][r], mx[r]);
          float corr = EXP2(m_run[q][r] - mn);
          l_run[q][r] *= corr;
          m_run[q][r] = mn;
          for (int nb = 0; nb < 8; ++nb) acc[q][nb][r] *= corr;
        }
      }
      for (int r = 0; r < 4; ++r) {
        float rs = 0.f;
        for (int kt = 0; kt < 4; ++kt) {
          float p = EXP2(s[q][kt][r] - m_run[q][r]);
          s[q][kt][r] = p;
          rs += p;
        }
        l_run[q][r] += dpp_add16(rs);
      }
    }

    // P -> swizzled LDS tile (write granule (2kt+(lr>>3))^(q&7))
    for (int q = 0; q < 2; ++q)
      for (int kt = 0; kt < 4; ++kt)
        for (int r = 0; r < 4; ++r) {
          int qrow = lg * 4 + r;
          int g = (2 * kt + (lr >> 3)) ^ (qrow & 7);
          *(f16*)(Pt[q] + qrow * 128 + g * 16 + (lr & 7) * 2) = (f16)s[q][kt][r];
        }
    asm volatile("s_waitcnt lgkmcnt(0)" ::: "memory");
    __builtin_amdgcn_sched_barrier(0);
    half8 af[2][2];
    for (int q = 0; q < 2; ++q)
      for (int kst = 0; kst < 2; ++kst)
        af[q][kst] = *(const half8*)(Pt[q] + lr * 128 + (((kst * 4 + lg) ^ (lr & 7)) << 4));

    // issue V(kb+1); target buffer's last reader (PV kb-1) done before B1(kb)
#pragma unroll
    for (int inst = 0; inst < 8; ++inst) {
      int t = inst * 128 + tid;
      int row = t >> 3, sp = t & 7, sl = sp ^ (row & 7);
      gload_lds16(Vb + (size_t)row * NN + keyn + sl * 8, Vn + t * 16);
    }
    asm volatile("s_waitcnt vmcnt(16)" ::: "memory");  // V(kb) done; K/V(kb+1) in flight
    __builtin_amdgcn_sched_barrier(0);
    __builtin_amdgcn_s_barrier();  // B2
    __builtin_amdgcn_sched_barrier(0);

    // PV: vf read once, both q-tiles consume
    __builtin_amdgcn_s_setprio(1);
    for (int nb = 0; nb < 8; ++nb)
      for (int kst = 0; kst < 2; ++kst) {
        half8 vf = *(const half8*)(Vc + (nb * 16 + lr) * 128 + (((kst * 4 + lg) ^ (lr & 7)) << 4));
        for (int q = 0; q < 2; ++q) acc[q][nb] = mfma16(af[q][kst], vf, acc[q][nb]);
      }
    __builtin_amdgcn_s_setprio(0);
  }
  asm volatile("s_waitcnt vmcnt(0)" ::: "memory");

  f16* Yb = Y + (size_t)b * NN * DD;
  for (int q = 0; q < 2; ++q) {
    float inv_l[4];
    for (int r = 0; r < 4; ++r) inv_l[r] = 1.f / l_run[q][r];
    for (int nb = 0; nb < 8; ++nb)
      for (int r = 0; r < 4; ++r)
        Yb[(size_t)(q0 + q * 16 + lg * 4 + r) * DD + nb * 16 + lr] = (f16)(acc[q][nb][r] * inv_l[r]);
  }
}

// ---------- output projection + fused BN partial stats ----------
__global__ __launch_bounds__(256) void k_gemm2(const f16* __restrict__ Y, const f16* __restrict__ Wwh,
                                               const float* __restrict__ wb, float* __restrict__ wy,
                                               float* __restrict__ stats) {
  __shared__ float part[2][8][64];
  int lane = threadIdx.x & 63, wave = threadIdx.x >> 6;
  int lr = lane & 15, lg = lane >> 4;
  int wr = wave >> 1, wc = wave & 1;
  int c0 = blockIdx.y * 64 + wc * 32;
  half8 w[4][2];
  for (int k0 = 0; k0 < 4; ++k0)
    for (int j = 0; j < 2; ++j)
      w[k0][j] = *(const half8*)(Wwh + (size_t)(c0 + j * 16 + lr) * DD + k0 * 32 + lg * 8);
  float bias[2];
  for (int j = 0; j < 2; ++j) bias[j] = wb[c0 + j * 16 + lr];
  float ps[2][2] = {};
  for (int mt = 0; mt < 8; ++mt) {
    int m0 = (blockIdx.x * 8 + mt) * 64 + wr * 32;
    f32x4 acc[2][2] = {};
    for (int k0 = 0; k0 < 4; ++k0) {
      half8 a[2];
      for (int i = 0; i < 2; ++i)
        a[i] = *(const half8*)(Y + (size_t)(m0 + i * 16 + lr) * DD + k0 * 32 + lg * 8);
      for (int i = 0; i < 2; ++i)
        for (int j = 0; j < 2; ++j)
          acc[i][j] = mfma16(a[i], w[k0][j], acc[i][j]);
    }
    for (int i = 0; i < 2; ++i)
      for (int j = 0; j < 2; ++j)
        for (int r = 0; r < 4; ++r) {
          int row = m0 + i * 16 + lg * 4 + r;
          int col = c0 + j * 16 + lr;
          float v = acc[i][j][r] + bias[j];
          wy[(size_t)row * CC + col] = v;
          ps[j][0] += v;
          ps[j][1] += v * v;
        }
  }
  for (int j = 0; j < 2; ++j) {
    int colL = wc * 32 + j * 16 + lr;
    part[0][wr * 4 + lg][colL] = ps[j][0];
    part[1][wr * 4 + lg][colL] = ps[j][1];
  }
  __syncthreads();
  if (threadIdx.x < 128) {
    int metric = threadIdx.x >> 6, col = threadIdx.x & 63;
    float s = 0.f;
    for (int wtr = 0; wtr < 8; ++wtr) s += part[metric][wtr][col];
    atomicAdd(&stats[metric * CC + blockIdx.y * 64 + col], s);
  }
}

// ---------- BN apply + residual ----------
__global__ void k_bn_apply(const float* __restrict__ wy, const float* __restrict__ x,
                           const float* __restrict__ stats, const float* __restrict__ gamma,
                           const float* __restrict__ beta, float* __restrict__ out) {
  __shared__ float tile[32][33];
  int b = blockIdx.z, c0 = blockIdx.y * 32, n0 = blockIdx.x * 32;
  int tx = threadIdx.x, ty = threadIdx.y;
  for (int j = 0; j < 4; ++j) {
    int nn = ty + j * 8;
    tile[nn][tx] = wy[((size_t)b * NN + n0 + nn) * CC + c0 + tx];
  }
  __syncthreads();
  const float inv_cnt = 1.f / (float)(BB * NN);
  for (int j = 0; j < 4; ++j) {
    int cc = ty + j * 8;
    int c = c0 + cc;
    float mean = stats[c] * inv_cnt;
    float var = stats[CC + c] * inv_cnt - mean * mean;
    float scale = gamma[c] * rsqrtf(var + BN_EPS);
    size_t oi = ((size_t)b * CC + c) * NN + n0 + tx;
    out[oi] = (tile[tx][cc] - mean) * scale + beta[c] + x[oi];
  }
}

extern "C" void kernel_launch(void* const* d_in, const int* in_sizes, int n_in,
                              void* d_out, int out_size, void* d_ws, size_t ws_size,
                              hipStream_t stream) {
  const float* x = (const float*)d_in[0];
  const float* tw = (const float*)d_in[1];
  const float* pw = (const float*)d_in[2];
  const float* gw = (const float*)d_in[3];
  const float* ww = (const float*)d_in[4];
  const float* wb = (const float*)d_in[5];
  const float* gamma = (const float*)d_in[6];
  const float* beta = (const float*)d_in[7];
  float* out = (float*)d_out;
  char* ws = (char*)d_ws;

  f16* Wcat = (f16*)(ws + 0);
  f16* Wwh = (f16*)(ws + 196608);
  float* stats = (float*)(ws + 262144);
  const size_t BASE = 1 << 20;
  f16* T = (f16*)(ws + BASE);
  f16* P = (f16*)(ws + BASE + 8388608);
  f16* Gdn = (f16*)(ws + BASE + 16777216);
  f16* Y = (f16*)(ws + BASE + 25165824);
  f16* xT = (f16*)(ws + BASE + 33554432);
  f16* Gnd = (f16*)(ws + BASE + 33554432 + 16777216);
  float* wy = (float*)(ws + BASE + 33554432);

  k_cast_weights<<<512, 256, 0, stream>>>(tw, pw, gw, ww, Wcat, Wwh, stats);
  k_transpose_x<<<dim3(NN / 32, CC / 32, BB), dim3(32, 8), 0, stream>>>(x, xT);
  k_gemm1<<<dim3(NN / 64, 384 / 64, BB), 256, 0, stream>>>(xT, Wcat, T, P, Gnd);
  k_transpose_g<<<dim3(NN / 32, DD / 32, BB), dim3(32, 8), 0, stream>>>(Gnd, Gdn);
  k_flash<<<512, 128, 0, stream>>>(T, P, Gdn, Y);
  k_gemm2<<<dim3(BB * NN / 512, CC / 64), 256, 0, stream>>>(Y, Wwh, wb, wy, stats);
  k_bn_apply<<<dim3(NN / 32, CC / 32, BB), dim3(32, 8), 0, stream>>>(wy, x, stats, gamma, beta, out);
}

// Round 6
// 209.990 us; speedup vs baseline: 1.1912x; 1.1912x over previous
//
#include <hip/hip_runtime.h>

#define BB 8
#define CC 256
#define DD 128
#define NN 4096
#define BN_EPS 1e-5f

typedef _Float16 f16;
typedef _Float16 half8 __attribute__((ext_vector_type(8)));
typedef _Float16 half2t __attribute__((ext_vector_type(2)));
typedef float f32x4 __attribute__((ext_vector_type(4)));

__device__ __forceinline__ f32x4 mfma16(half8 a, half8 b, f32x4 c) {
  return __builtin_amdgcn_mfma_f32_16x16x32_f16(a, b, c, 0, 0, 0);
}

__device__ __forceinline__ void gload_lds16(const void* g, void* l) {
  __builtin_amdgcn_global_load_lds((const __attribute__((address_space(1))) void*)g,
                                   (__attribute__((address_space(3))) void*)l, 16, 0, 0);
}

__device__ __forceinline__ half2t pkrtz(float a, float b) {
  auto t = __builtin_amdgcn_cvt_pkrtz(a, b);
  return __builtin_bit_cast(half2t, t);
}

#define EXP2(x) __builtin_amdgcn_exp2f(x)

// key permutation: makes swapped-QK register layout feed PV A-fragment with zero data movement
#define PERM(i) ((((i) >> 5) & 1) * 32 + (((i) >> 2) & 3) * 8 + (((i) >> 4) & 1) * 4 + ((i) & 3))

// ---------- weights cast (fp32 -> fp16), stats zero ----------
__global__ void k_cast_weights(const float* __restrict__ tw, const float* __restrict__ pw,
                               const float* __restrict__ gw, const float* __restrict__ ww,
                               f16* __restrict__ Wcat, f16* __restrict__ Wwh,
                               float* __restrict__ stats) {
  int i = blockIdx.x * 256 + threadIdx.x;
  if (i < 32768) Wcat[i] = (f16)tw[i];
  else if (i < 65536) Wcat[i] = (f16)pw[i - 32768];
  else if (i < 98304) Wcat[i] = (f16)gw[i - 65536];
  else if (i < 131072) Wwh[i - 98304] = (f16)ww[i - 98304];
  if (i < 512) stats[i] = 0.f;
}

// ---------- x [B][C][N] f32 -> xT [B][N][C] f16 ----------
__global__ void k_transpose_x(const float* __restrict__ x, f16* __restrict__ xT) {
  __shared__ f16 tile[32][33];
  int b = blockIdx.z, c0 = blockIdx.y * 32, n0 = blockIdx.x * 32;
  int tx = threadIdx.x, ty = threadIdx.y;
  const float* xp = x + ((size_t)b * CC + c0) * NN + n0;
  for (int j = 0; j < 4; ++j) {
    int cc = ty + j * 8;
    tile[cc][tx] = (f16)xp[(size_t)cc * NN + tx];
  }
  __syncthreads();
  f16* xo = xT + ((size_t)b * NN + n0) * CC + c0;
  for (int j = 0; j < 4; ++j) {
    int nn = ty + j * 8;
    xo[(size_t)nn * CC + tx] = tile[tx][nn];
  }
}

// ---------- projections ----------
__global__ __launch_bounds__(256) void k_gemm1(const f16* __restrict__ xT, const f16* __restrict__ Wcat,
                                               f16* __restrict__ T, f16* __restrict__ P,
                                               f16* __restrict__ Gnd) {
  int b = blockIdx.z;
  int lane = threadIdx.x & 63, wave = threadIdx.x >> 6;
  int lr = lane & 15, lg = lane >> 4;
  int wr = wave >> 1, wc = wave & 1;
  int m0 = blockIdx.x * 64 + wr * 32;
  int c0 = blockIdx.y * 64 + wc * 32;
  const f16* A = xT + (size_t)b * NN * CC;
  f32x4 acc[2][2] = {};
  for (int k0 = 0; k0 < CC; k0 += 32) {
    half8 a[2], w[2];
    for (int i = 0; i < 2; ++i)
      a[i] = *(const half8*)(A + (size_t)(m0 + i * 16 + lr) * CC + k0 + lg * 8);
    for (int j = 0; j < 2; ++j)
      w[j] = *(const half8*)(Wcat + (size_t)(c0 + j * 16 + lr) * CC + k0 + lg * 8);
    for (int i = 0; i < 2; ++i)
      for (int j = 0; j < 2; ++j)
        acc[i][j] = mfma16(a[i], w[j], acc[i][j]);
  }
  for (int i = 0; i < 2; ++i)
    for (int j = 0; j < 2; ++j)
      for (int r = 0; r < 4; ++r) {
        int row = m0 + i * 16 + lg * 4 + r;
        int col = c0 + j * 16 + lr;
        f16 v = (f16)acc[i][j][r];
        size_t base = (size_t)b * NN + row;
        if (col < DD) T[base * DD + col] = v;
        else if (col < 2 * DD) P[base * DD + col - DD] = v;
        else Gnd[base * DD + col - 2 * DD] = v;
      }
}

// ---------- Gnd [B][N][D] -> Gdn [B][D][N] ----------
__global__ void k_transpose_g(const f16* __restrict__ Gnd, f16* __restrict__ Gdn) {
  __shared__ f16 tile[32][33];
  int b = blockIdx.z, d0 = blockIdx.y * 32, n0 = blockIdx.x * 32;
  int tx = threadIdx.x, ty = threadIdx.y;
  for (int j = 0; j < 4; ++j) {
    int nn = ty + j * 8;
    tile[nn][tx] = Gnd[((size_t)b * NN + n0 + nn) * DD + d0 + tx];
  }
  __syncthreads();
  for (int j = 0; j < 4; ++j) {
    int dd = ty + j * 8;
    Gdn[((size_t)b * DD + d0 + dd) * NN + n0 + tx] = tile[tx][dd];
  }
}

// ---------- flash attention ----------
// 4 waves/block, 16 q rows/wave; KV block 64. Swapped QK: mfma(K,Q) -> lane holds S^T
// for q = q0+lane&15; K rows staged in PERM order so PV A-fragment = pack of own regs.
// LDS: K dbuf 2x16KB + V dbuf 2x16KB (XOR-swizzled) = 64KB -> 2 blocks/CU.
// Sync: 2 barriers/iter, counted vmcnt(8); never drained mid-loop.
// Softmax in exp2 domain (Q pre-scaled by log2e); defer-max THR = 11.5.
__global__ __launch_bounds__(256) void k_flash(const f16* __restrict__ T, const f16* __restrict__ P,
                                               const f16* __restrict__ Gdn, f16* __restrict__ Y) {
  __shared__ char smem[65536];
  int bid = blockIdx.x;
  int b = bid & 7;  // batch -> XCD pinning
  int qx = bid >> 3;
  int tid = threadIdx.x;
  int lane = tid & 63, wave = tid >> 6;
  int lr = lane & 15, lg = lane >> 4;
  int q0 = qx * 64 + wave * 16;
  const f16* Tb = T + (size_t)b * NN * DD;
  const f16* Pb = P + (size_t)b * NN * DD;
  const f16* Vb = Gdn + (size_t)b * DD * NN;
  int srcq = 4 * lg;  // base lane for per-acc-row softmax-state redistribution

  half8 qf[4];
  for (int ks = 0; ks < 4; ++ks) {
    half8 v = *(const half8*)(Tb + (size_t)(q0 + lr) * DD + ks * 32 + lg * 8);
    for (int j = 0; j < 8; ++j) v[j] *= (f16)1.44269504f;  // log2(e) into Q
    qf[ks] = v;
  }
  f32x4 acc[8] = {};
  float m_run = -1e30f, l_run = 0.f;  // per-lane state for q = q0 + lr

  // prologue: stage K(0) (PERM rows), V(0)
  for (int inst = 0; inst < 4; ++inst) {
    int t = inst * 256 + tid;
    int row = t >> 4, sp = t & 15, sl = sp ^ (row & 7);
    gload_lds16(Pb + (size_t)PERM(row) * DD + sl * 8, smem + (inst * 256 + wave * 64) * 16);
  }
  for (int inst = 0; inst < 4; ++inst) {
    int t = inst * 256 + tid;
    int row = t >> 3, sp = t & 7, sl = sp ^ (row & 7);
    gload_lds16(Vb + (size_t)row * NN + sl * 8, smem + 32768 + (inst * 256 + wave * 64) * 16);
  }

  for (int kb = 0; kb < 64; ++kb) {
    int key0 = kb * 64;
    int keyn = (kb < 63) ? key0 + 64 : 0;  // last prefetch harmless
    char* Kc = smem + (kb & 1) * 16384;
    char* Kn = smem + ((kb + 1) & 1) * 16384;
    char* Vc = smem + 32768 + (kb & 1) * 16384;
    char* Vn = smem + 32768 + ((kb + 1) & 1) * 16384;

    // issue K(kb+1); its target buffer's last reader (QK kb-1) finished before B2(kb-1)
    for (int inst = 0; inst < 4; ++inst) {
      int t = inst * 256 + tid;
      int row = t >> 4, sp = t & 15, sl = sp ^ (row & 7);
      gload_lds16(Pb + (size_t)(keyn + PERM(row)) * DD + sl * 8, Kn + (inst * 256 + wave * 64) * 16);
    }
    asm volatile("s_waitcnt vmcnt(8)" ::: "memory");  // K(kb) done; V(kb)+K(kb+1) in flight
    __builtin_amdgcn_sched_barrier(0);
    __builtin_amdgcn_s_barrier();  // B1
    __builtin_amdgcn_sched_barrier(0);

    // QK^T swapped: s[kt][r] = S[key o(16kt+4lg+r)][q0+lr]
    f32x4 s[4];
    __builtin_amdgcn_s_setprio(1);
    for (int kt = 0; kt < 4; ++kt) {
      f32x4 t = {};
      for (int ks = 0; ks < 4; ++ks) {
        half8 kf = *(const half8*)(Kc + (kt * 16 + lr) * 256 + (((ks * 4 + lg) ^ (lr & 7)) << 4));
        t = mfma16(kf, qf[ks], t);
      }
      s[kt] = t;
    }
    __builtin_amdgcn_s_setprio(0);

    // softmax (log2 domain): in-register tree + 2 cross-lane ops
    float mx = fmaxf(fmaxf(s[0][0], s[0][1]), fmaxf(s[0][2], s[0][3]));
    mx = fmaxf(mx, fmaxf(fmaxf(s[1][0], s[1][1]), fmaxf(s[1][2], s[1][3])));
    mx = fmaxf(mx, fmaxf(fmaxf(s[2][0], s[2][1]), fmaxf(s[2][2], s[2][3])));
    mx = fmaxf(mx, fmaxf(fmaxf(s[3][0], s[3][1]), fmaxf(s[3][2], s[3][3])));
    mx = fmaxf(mx, __shfl_xor(mx, 16));
    mx = fmaxf(mx, __shfl_xor(mx, 32));
    bool grow = mx > m_run + 11.5f;
    if (__ballot(grow)) {
      float mn = fmaxf(m_run, mx);
      float corr = EXP2(m_run - mn);
      l_run *= corr;
      m_run = mn;
      float c0 = __shfl(corr, srcq + 0), c1 = __shfl(corr, srcq + 1);
      float c2 = __shfl(corr, srcq + 2), c3 = __shfl(corr, srcq + 3);
      for (int nb = 0; nb < 8; ++nb) {
        acc[nb][0] *= c0; acc[nb][1] *= c1; acc[nb][2] *= c2; acc[nb][3] *= c3;
      }
    }
    float rs = 0.f;
    for (int kt = 0; kt < 4; ++kt)
      for (int r = 0; r < 4; ++r) {
        float p = EXP2(s[kt][r] - m_run);
        s[kt][r] = p;
        rs += p;
      }
    rs += __shfl_xor(rs, 16);
    rs += __shfl_xor(rs, 32);
    l_run += rs;

    // PV A-fragment = pack of own registers (enabled by PERM staging)
    half8 af[2];
    for (int kst = 0; kst < 2; ++kst) {
      union { half8 h8; half2t h2[4]; } u;
      u.h2[0] = pkrtz(s[2 * kst][0], s[2 * kst][1]);
      u.h2[1] = pkrtz(s[2 * kst][2], s[2 * kst][3]);
      u.h2[2] = pkrtz(s[2 * kst + 1][0], s[2 * kst + 1][1]);
      u.h2[3] = pkrtz(s[2 * kst + 1][2], s[2 * kst + 1][3]);
      af[kst] = u.h8;
    }

    // issue V(kb+1); its target buffer's last reader (PV kb-1) finished before B1(kb)
    for (int inst = 0; inst < 4; ++inst) {
      int t = inst * 256 + tid;
      int row = t >> 3, sp = t & 7, sl = sp ^ (row & 7);
      gload_lds16(Vb + (size_t)row * NN + keyn + sl * 8, Vn + (inst * 256 + wave * 64) * 16);
    }
    asm volatile("s_waitcnt vmcnt(8)" ::: "memory");  // V(kb) done; K/V(kb+1) in flight
    __builtin_amdgcn_sched_barrier(0);
    __builtin_amdgcn_s_barrier();  // B2
    __builtin_amdgcn_sched_barrier(0);

    // PV (V in original key order; PERM self-cancels on the B side)
    __builtin_amdgcn_s_setprio(1);
    for (int nb = 0; nb < 8; ++nb)
      for (int kst = 0; kst < 2; ++kst) {
        half8 vf = *(const half8*)(Vc + (nb * 16 + lr) * 128 + (((kst * 4 + lg) ^ (lr & 7)) << 4));
        acc[nb] = mfma16(af[kst], vf, acc[nb]);
      }
    __builtin_amdgcn_s_setprio(0);
  }
  asm volatile("s_waitcnt vmcnt(0)" ::: "memory");

  float il[4];
  for (int r = 0; r < 4; ++r) il[r] = 1.f / __shfl(l_run, srcq + r);
  f16* Yb = Y + (size_t)b * NN * DD;
  for (int nb = 0; nb < 8; ++nb)
    for (int r = 0; r < 4; ++r)
      Yb[(size_t)(q0 + lg * 4 + r) * DD + nb * 16 + lr] = (f16)(acc[nb][r] * il[r]);
}

// ---------- output projection + fused BN partial stats ----------
__global__ __launch_bounds__(256) void k_gemm2(const f16* __restrict__ Y, const f16* __restrict__ Wwh,
                                               const float* __restrict__ wb, float* __restrict__ wy,
                                               float* __restrict__ stats) {
  __shared__ float part[2][8][64];
  int lane = threadIdx.x & 63, wave = threadIdx.x >> 6;
  int lr = lane & 15, lg = lane >> 4;
  int wr = wave >> 1, wc = wave & 1;
  int c0 = blockIdx.y * 64 + wc * 32;
  half8 w[4][2];
  for (int k0 = 0; k0 < 4; ++k0)
    for (int j = 0; j < 2; ++j)
      w[k0][j] = *(const half8*)(Wwh + (size_t)(c0 + j * 16 + lr) * DD + k0 * 32 + lg * 8);
  float bias[2];
  for (int j = 0; j < 2; ++j) bias[j] = wb[c0 + j * 16 + lr];
  float ps[2][2] = {};
  for (int mt = 0; mt < 8; ++mt) {
    int m0 = (blockIdx.x * 8 + mt) * 64 + wr * 32;
    f32x4 acc[2][2] = {};
    for (int k0 = 0; k0 < 4; ++k0) {
      half8 a[2];
      for (int i = 0; i < 2; ++i)
        a[i] = *(const half8*)(Y + (size_t)(m0 + i * 16 + lr) * DD + k0 * 32 + lg * 8);
      for (int i = 0; i < 2; ++i)
        for (int j = 0; j < 2; ++j)
          acc[i][j] = mfma16(a[i], w[k0][j], acc[i][j]);
    }
    for (int i = 0; i < 2; ++i)
      for (int j = 0; j < 2; ++j)
        for (int r = 0; r < 4; ++r) {
          int row = m0 + i * 16 + lg * 4 + r;
          int col = c0 + j * 16 + lr;
          float v = acc[i][j][r] + bias[j];
          wy[(size_t)row * CC + col] = v;
          ps[j][0] += v;
          ps[j][1] += v * v;
        }
  }
  for (int j = 0; j < 2; ++j) {
    int colL = wc * 32 + j * 16 + lr;
    part[0][wr * 4 + lg][colL] = ps[j][0];
    part[1][wr * 4 + lg][colL] = ps[j][1];
  }
  __syncthreads();
  if (threadIdx.x < 128) {
    int metric = threadIdx.x >> 6, col = threadIdx.x & 63;
    float s = 0.f;
    for (int wtr = 0; wtr < 8; ++wtr) s += part[metric][wtr][col];
    atomicAdd(&stats[metric * CC + blockIdx.y * 64 + col], s);
  }
}

// ---------- BN apply + residual ----------
__global__ void k_bn_apply(const float* __restrict__ wy, const float* __restrict__ x,
                           const float* __restrict__ stats, const float* __restrict__ gamma,
                           const float* __restrict__ beta, float* __restrict__ out) {
  __shared__ float tile[32][33];
  int b = blockIdx.z, c0 = blockIdx.y * 32, n0 = blockIdx.x * 32;
  int tx = threadIdx.x, ty = threadIdx.y;
  for (int j = 0; j < 4; ++j) {
    int nn = ty + j * 8;
    tile[nn][tx] = wy[((size_t)b * NN + n0 + nn) * CC + c0 + tx];
  }
  __syncthreads();
  const float inv_cnt = 1.f / (float)(BB * NN);
  for (int j = 0; j < 4; ++j) {
    int cc = ty + j * 8;
    int c = c0 + cc;
    float mean = stats[c] * inv_cnt;
    float var = stats[CC + c] * inv_cnt - mean * mean;
    float scale = gamma[c] * rsqrtf(var + BN_EPS);
    size_t oi = ((size_t)b * CC + c) * NN + n0 + tx;
    out[oi] = (tile[tx][cc] - mean) * scale + beta[c] + x[oi];
  }
}

extern "C" void kernel_launch(void* const* d_in, const int* in_sizes, int n_in,
                              void* d_out, int out_size, void* d_ws, size_t ws_size,
                              hipStream_t stream) {
  const float* x = (const float*)d_in[0];
  const float* tw = (const float*)d_in[1];
  const float* pw = (const float*)d_in[2];
  const float* gw = (const float*)d_in[3];
  const float* ww = (const float*)d_in[4];
  const float* wb = (const float*)d_in[5];
  const float* gamma = (const float*)d_in[6];
  const float* beta = (const float*)d_in[7];
  float* out = (float*)d_out;
  char* ws = (char*)d_ws;

  f16* Wcat = (f16*)(ws + 0);
  f16* Wwh = (f16*)(ws + 196608);
  float* stats = (float*)(ws + 262144);
  const size_t BASE = 1 << 20;
  f16* T = (f16*)(ws + BASE);
  f16* P = (f16*)(ws + BASE + 8388608);
  f16* Gdn = (f16*)(ws + BASE + 16777216);
  f16* Y = (f16*)(ws + BASE + 25165824);
  f16* xT = (f16*)(ws + BASE + 33554432);
  f16* Gnd = (f16*)(ws + BASE + 33554432 + 16777216);
  float* wy = (float*)(ws + BASE + 33554432);

  k_cast_weights<<<512, 256, 0, stream>>>(tw, pw, gw, ww, Wcat, Wwh, stats);
  k_transpose_x<<<dim3(NN / 32, CC / 32, BB), dim3(32, 8), 0, stream>>>(x, xT);
  k_gemm1<<<dim3(NN / 64, 384 / 64, BB), 256, 0, stream>>>(xT, Wcat, T, P, Gnd);
  k_transpose_g<<<dim3(NN / 32, DD / 32, BB), dim3(32, 8), 0, stream>>>(Gnd, Gdn);
  k_flash<<<512, 256, 0, stream>>>(T, P, Gdn, Y);
  k_gemm2<<<dim3(BB * NN / 512, CC / 64), 256, 0, stream>>>(Y, Wwh, wb, wy, stats);
  k_bn_apply<<<dim3(NN / 32, CC / 32, BB), dim3(32, 8), 0, stream>>>(wy, x, stats, gamma, beta, out);
}